// Round 4
// baseline (160.696 us; speedup 1.0000x reference)
//
#include <hip/hip_runtime.h>
#include <math.h>

// Problem constants (from reference): B=32, Q=4096, G=32, C=128
#define NB   32
#define BQ   4096
#define GMAX 32
#define NC   128
#define BS   512            // solver threads per block
#define CPT  (BQ / BS)      // 8 contiguous columns per thread: j = tid*8 + k
#define NWAVE (BS / 64)     // 8 waves

#define TQ   32             // q-tile per build block
#define BBS  256            // build block size
#define NTILE (BQ / TQ)     // 128 q-tiles per batch

// ---------------- Kernel 1: per-row partial argmin over cost ---------------
// cost[b][i][q] = -sem[b,q,lab_i] - 0.5*obj[b,q] + cent[b,q,i] - 2*giou[b,q,i]
// exact f32 per-op rounding in reference order. The cost matrix itself is
// NEVER materialized: its only consumer is the rare Dijkstra augmentation
// path (~0.12 rows/batch expected), which recomputes rows on the fly in the
// matcher. This kernel emits only pmin[b][i][qtile] = packed
// (monotone(f32 cost) << 32 | q) partial min over this block's 32 columns.
__launch_bounds__(BBS)
__global__ void build_min_kernel(const float* __restrict__ sem,
                                 const float* __restrict__ objp,
                                 const float* __restrict__ cent,
                                 const float* __restrict__ giou,
                                 const int*   __restrict__ labels,
                                 const int*   __restrict__ nact,
                                 unsigned long long* __restrict__ pmin) // [B][G][NTILE]
{
    const int b  = blockIdx.y;
    const int qt = blockIdx.x;
    const int q0 = qt * TQ;
    const int tid = threadIdx.x;

    __shared__ float cent_sh[TQ][GMAX + 1];
    __shared__ float giou_sh[TQ][GMAX + 1];
    __shared__ int lab_sh[GMAX];

    if (tid < GMAX) lab_sh[tid] = labels[b * GMAX + tid];
    const int ng = nact[b];

    {
        const float4* centb = (const float4*)(cent + ((size_t)b * BQ + q0) * GMAX);
        const float4* gioub = (const float4*)(giou + ((size_t)b * BQ + q0) * GMAX);
        int r = tid;   // TQ*GMAX/4 == 256 == BBS
        float4 cv = centb[r];
        float4 gv = gioub[r];
        int e = r * 4;
        int qq = e >> 5;
        int ii = e & (GMAX - 1);
        cent_sh[qq][ii]     = cv.x;
        cent_sh[qq][ii + 1] = cv.y;
        cent_sh[qq][ii + 2] = cv.z;
        cent_sh[qq][ii + 3] = cv.w;
        giou_sh[qq][ii]     = gv.x;
        giou_sh[qq][ii + 1] = gv.y;
        giou_sh[qq][ii + 2] = gv.z;
        giou_sh[qq][ii + 3] = gv.w;
    }
    __syncthreads();

    const int qi = tid & (TQ - 1);
    const int ig = tid >> 5;
    const int q  = q0 + qi;
    const float ho = __fmul_rn(0.5f, objp[b * BQ + q]);
    const float* semrow = sem + ((size_t)b * BQ + q) * NC;

    // issue all sem gathers first (uniform trip count => no divergence) for MLP
    float pc[4];
#pragma unroll
    for (int k = 0; k < 4; k++) {
        int i = ig + 8 * k;
        if (i < ng) pc[k] = semrow[lab_sh[i]];
    }

#pragma unroll
    for (int k = 0; k < 4; k++) {
        int i = ig + 8 * k;
        if (i >= ng) break;
        float ce = cent_sh[qi][i];
        float gi = giou_sh[qi][i];
        float c = __fsub_rn(__fadd_rn(__fsub_rn(-pc[k], ho), ce),
                            __fmul_rn(2.0f, gi));

        // partial (min, first-argmin) over this tile's 32 q's.
        // monotone u32 transform preserves <; u64 min == lex (value, q) min.
        unsigned cbits = __float_as_uint(c);
        unsigned mono  = (cbits & 0x80000000u) ? ~cbits : (cbits | 0x80000000u);
        unsigned long long key = ((unsigned long long)mono << 32) | (unsigned)q;
#pragma unroll
        for (int off = 16; off >= 1; off >>= 1) {
            unsigned long long ok = __shfl_down(key, off, 32);
            if (ok < key) key = ok;
        }
        if (qi == 0) pmin[((size_t)b * GMAX + i) * NTILE + qt] = key;
    }
}

// ---------------- Kernel 2: JV Hungarian solver with greedy warm start ----
// One block per batch. Dual-feasible warm start: u[i] = min_j cost[i][j],
// v = 0; greedy-assign each row to its (first-index) argmin column if free.
// Rows that collide run the exact f64 Dijkstra augmentation (first-index
// tie-break), recomputing cost rows on the fly from the raw inputs with the
// build's exact f32 op order (bit-identical values). Complementary slackness
// holds throughout => optimal assignment; unique optimum on continuous
// random costs => matches the reference.
__launch_bounds__(BS, 1)
__global__ void matcher_kernel(const float* __restrict__ sem,
                               const float* __restrict__ objp,
                               const float* __restrict__ cent,
                               const float* __restrict__ giou,
                               const int*   __restrict__ labels,
                               const unsigned long long* __restrict__ pmin,
                               const int*   __restrict__ nact,   // [B]
                               float* __restrict__ out)          // [2*B*Q]
{
    const int b    = blockIdx.x;
    const int tid  = threadIdx.x;
    const int m    = BQ;
    const int wave = tid >> 6;
    const int lane = tid & 63;

    __shared__ __align__(16) short p_lds[BQ + 8];       // matched row per col
    __shared__ __align__(16) unsigned short way_lds[BQ];
    __shared__ double u_lds[GMAX];
    __shared__ double   redv[2][NWAVE];
    __shared__ unsigned redpk[2][NWAVE];
    __shared__ int    step_i0[GMAX + 2];
    __shared__ double step_D[GMAX + 2];
    __shared__ float  rmin_v[GMAX];
    __shared__ int    rmin_j[GMAX];
    __shared__ int    lab_sh[GMAX];
    __shared__ int    unmatched[GMAX];
    __shared__ int    s_nunm;

    {   // vectorized init: 512 threads x 16B == 8192 B == BQ shorts; 16B tail
        int4 mone; mone.x = mone.y = mone.z = mone.w = -1;
        ((int4*)p_lds)[tid] = mone;
        if (tid < 4) ((int*)(p_lds + BQ))[tid] = -1;
    }
    if (tid < GMAX) lab_sh[tid] = labels[b * GMAX + tid];
    const int ng = nact[b];
    __syncthreads();

    // ---- Pass 1: reduce the build kernel's per-tile partial mins ----------
    // 128 u64 per row: 2 coalesced loads/lane + 6 shuffle steps per row.
    {
        const unsigned long long* pb = pmin + (size_t)b * GMAX * NTILE;
        for (int r = wave; r < ng; r += NWAVE) {
            const unsigned long long* row = pb + (size_t)r * NTILE;
            unsigned long long k0 = row[lane];
            unsigned long long k1 = row[lane + 64];
            unsigned long long key = (k1 < k0) ? k1 : k0;
#pragma unroll
            for (int off = 32; off >= 1; off >>= 1) {
                unsigned long long ok = __shfl_down(key, off, 64);
                if (ok < key) key = ok;
            }
            if (lane == 0) {
                unsigned mono = (unsigned)(key >> 32);
                unsigned bits = (mono & 0x80000000u) ? (mono ^ 0x80000000u) : ~mono;
                rmin_v[r] = __uint_as_float(bits);
                rmin_j[r] = (int)(key & 0xFFFFFFFFu);
            }
        }
    }
    __syncthreads();

    // ---- duals + greedy assignment (thread 0, <=32 iters) ----
    if (tid < ng) u_lds[tid] = (double)rmin_v[tid];
    if (tid == 0) {
        int nu = 0;
        for (int i = 0; i < ng; i++) {
            int j = rmin_j[i];
            if (p_lds[j] < 0) p_lds[j] = (short)i;
            else unmatched[nu++] = i;           // ascending row order
        }
        s_nunm = nu;
    }
    __syncthreads();
    const int nunm = s_nunm;

    const double INF = (double)INFINITY;
    const int jbase = tid * CPT;

    if (nunm > 0) {
        // per-thread row-invariant pieces: base pointers + 0.5*obj[j] (8 regs)
        const float* semb  = sem  + (size_t)b * BQ * NC;
        const float* centb = cent + (size_t)b * BQ * GMAX;
        const float* gioub = giou + (size_t)b * BQ * GMAX;
        float ho[CPT];
        {
            const float* ob = objp + (size_t)b * BQ + jbase;
#pragma unroll
            for (int k = 0; k < CPT; k++) ho[k] = __fmul_rn(0.5f, ob[k]);
        }

        double v_reg[CPT], minv[CPT], enterD[CPT];
        int way_reg[CPT], p_reg[CPT];
#pragma unroll
        for (int k = 0; k < CPT; k++) { v_reg[k] = 0.0; way_reg[k] = m; enterD[k] = 0.0; }

        // on-the-fly cost row 'i' for this thread's 8 columns; op order is
        // bit-identical to build_min_kernel's.
#define ROWCOMP(i, cf)                                                         \
        {                                                                      \
            const int li = lab_sh[i];                                          \
            _Pragma("unroll")                                                  \
            for (int k = 0; k < CPT; k++) {                                    \
                const size_t j = (size_t)(jbase + k);                          \
                float pcls = semb[j * NC + li];                                \
                float ce   = centb[j * GMAX + (i)];                            \
                float gi   = gioub[j * GMAX + (i)];                            \
                cf[k] = __fsub_rn(__fadd_rn(__fsub_rn(-pcls, ho[k]), ce),      \
                                  __fmul_rn(2.0f, gi));                        \
            }                                                                  \
        }

        for (int t = 0; t < nunm; t++) {
            const int ri = unmatched[t];

            // refresh p_reg (one ds_read_b128; p constant during the phase)
            int4 pv = ((const int4*)p_lds)[tid];
            p_reg[0] = (int)(short)(pv.x & 0xFFFF); p_reg[1] = pv.x >> 16;
            p_reg[2] = (int)(short)(pv.y & 0xFFFF); p_reg[3] = pv.y >> 16;
            p_reg[4] = (int)(short)(pv.z & 0xFFFF); p_reg[5] = pv.z >> 16;
            p_reg[6] = (int)(short)(pv.w & 0xFFFF); p_reg[7] = pv.w >> 16;

            // initial row (row ri) + its u
            float cf[CPT];
            ROWCOMP(ri, cf);
            double ui0 = u_lds[ri];

#pragma unroll
            for (int k = 0; k < CPT; k++) minv[k] = INF;
            unsigned used_mask = 0;
            int i0 = ri, j0 = m, ns = 0, buf = 0, jfin;
            double D = 0.0;

            while (true) {
                // relax + per-thread lexicographic argmin (asc. k == asc. j)
                double bestv = INF;
                unsigned bestpk = ((unsigned)m << 8);
#pragma unroll
                for (int k = 0; k < CPT; k++) {
                    bool un = !((used_mask >> k) & 1u);
                    double cur = ((double)cf[k] - ui0) - v_reg[k];
                    bool better = un && (cur < minv[k]);
                    if (better) { minv[k] = cur; way_reg[k] = j0; }
                    double mv = un ? minv[k] : INF;
                    if (mv < bestv) {
                        bestv = mv;
                        bestpk = (((unsigned)(jbase + k)) << 8) | (unsigned)(p_reg[k] + 1);
                    }
                }

                // wave-level lexicographic (val, packed-j) min
#pragma unroll
                for (int off = 32; off >= 1; off >>= 1) {
                    double   ov  = __shfl_down(bestv, off, 64);
                    unsigned opk = __shfl_down(bestpk, off, 64);
                    if (ov < bestv || (ov == bestv && opk < bestpk)) { bestv = ov; bestpk = opk; }
                }
                if (lane == 0) { redv[buf][wave] = bestv; redpk[buf][wave] = bestpk; }
                __syncthreads();                               // the ONLY barrier

                // redundant final reduce on every thread (LDS broadcast reads)
                double delta = redv[buf][0]; unsigned pk = redpk[buf][0];
#pragma unroll
                for (int w = 1; w < NWAVE; w++) {
                    double ov = redv[buf][w]; unsigned opk = redpk[buf][w];
                    if (ov < delta || (ov == delta && opk < pk)) { delta = ov; pk = opk; }
                }
                const int j1 = (int)(pk >> 8);
                const int pi = (int)(pk & 0xFFu) - 1;

                if (tid == 0) { step_i0[ns] = i0; step_D[ns] = D; }
                D += delta;
                ns++;

                if (pi < 0) { jfin = j1; break; }

                // next row computed under the update shadow
                ROWCOMP(pi, cf);
                ui0 = u_lds[pi];

#pragma unroll
                for (int k = 0; k < CPT; k++)
                    if (!((used_mask >> k) & 1u)) minv[k] -= delta;

                unsigned kk = (unsigned)(j1 - jbase);
                if (kk < CPT) { used_mask |= (1u << kk); enterD[kk] = D; }

                i0 = pi; j0 = j1; buf ^= 1;
            }

            // closed-form dual updates (same f64 values as per-step updates)
#pragma unroll
            for (int k = 0; k < CPT; k++)
                if ((used_mask >> k) & 1u) { v_reg[k] -= (D - enterD[k]); }

            // dump way_reg as one packed 16B LDS write
            int4 wv;
            wv.x = (way_reg[0] & 0xFFFF) | (way_reg[1] << 16);
            wv.y = (way_reg[2] & 0xFFFF) | (way_reg[3] << 16);
            wv.z = (way_reg[4] & 0xFFFF) | (way_reg[5] << 16);
            wv.w = (way_reg[6] & 0xFFFF) | (way_reg[7] << 16);
            ((int4*)way_lds)[tid] = wv;

            __syncthreads();   // way/step logs visible to all
            if (tid < ns) u_lds[step_i0[tid]] += D - step_D[tid];  // distinct rows
            if (tid == 0) {
                int jc = jfin;
                while (jc != m) {
                    int jp = (int)way_lds[jc];
                    p_lds[jc] = (jp == m) ? (short)ri : p_lds[jp];
                    jc = jp;
                }
            }
            __syncthreads();
        }
#undef ROWCOMP
    }

    // ---- write outputs: [per_prop (B*Q), mask (B*Q)] as float ----
#pragma unroll
    for (int k = 0; k < CPT; k++) {
        int j = jbase + k;
        short pj = p_lds[j];
        out[(size_t)b * BQ + j] = (pj >= 0) ? (float)pj : 0.0f;
        out[(size_t)NB * BQ + (size_t)b * BQ + j] = (pj >= 0) ? 1.0f : 0.0f;
    }
}

extern "C" void kernel_launch(void* const* d_in, const int* in_sizes, int n_in,
                              void* d_out, int out_size, void* d_ws, size_t ws_size,
                              hipStream_t stream) {
    const float* sem    = (const float*)d_in[0];  // [B,Q,C]
    const float* objp   = (const float*)d_in[1];  // [B,Q]
    const float* cent   = (const float*)d_in[2];  // [B,Q,G]
    const float* giou   = (const float*)d_in[3];  // [B,Q,G]
    const int*   labels = (const int*)d_in[4];    // [B,G]
    const int*   nact   = (const int*)d_in[5];    // [B]
    float* out  = (float*)d_out;                  // [2*B*Q]
    unsigned long long* pmin = (unsigned long long*)d_ws;  // [B][G][NTILE] = 1 MB

    dim3 bgrid(NTILE, NB);
    build_min_kernel<<<bgrid, BBS, 0, stream>>>(sem, objp, cent, giou,
                                                labels, nact, pmin);
    matcher_kernel<<<NB, BS, 0, stream>>>(sem, objp, cent, giou, labels,
                                          pmin, nact, out);
}

// Round 5
// 138.762 us; speedup vs baseline: 1.1581x; 1.1581x over previous
//
#include <hip/hip_runtime.h>
#include <math.h>

// Problem constants (from reference): B=32, Q=4096, G=32, C=128
#define NB   32
#define BQ   4096
#define GMAX 32
#define NC   128
#define BS   512            // solver threads per block
#define CPT  (BQ / BS)      // 8 contiguous columns per thread: j = tid*8 + k
#define NWAVE (BS / 64)     // 8 waves

#define TQ   32             // q-tile per build block
#define BBS  256            // build block size
#define NTILE (BQ / TQ)     // 128 q-tiles per batch

#define COST_BYTES ((size_t)NB * GMAX * BQ * 4)   // 16 MB

// ---------------- Kernel 1: cost build + fused per-row partial argmin ------
// cost[b][i][q] = -sem[b,q,lab_i] - 0.5*obj[b,q] + cent[b,q,i] - 2*giou[b,q,i]
// exact f32 per-op rounding in reference order. Only rows i < ng are written.
// sem values are gathered directly from global (no LDS staging: only the
// <=32 label columns of 128 classes are needed; staging the full tile wastes
// LDS, a barrier, and ~50% of the bytes). cost stores are nontemporal: the
// matrix is read only on the rare Dijkstra path, so don't evict L2/L3 with it.
// Also emits pmin[b][i][qtile] = packed (monotone(f32 cost) << 32 | q) partial
// min over this block's 32 columns.
__launch_bounds__(BBS)
__global__ void build_cost_kernel(const float* __restrict__ sem,
                                  const float* __restrict__ objp,
                                  const float* __restrict__ cent,
                                  const float* __restrict__ giou,
                                  const int*   __restrict__ labels,
                                  const int*   __restrict__ nact,
                                  float* __restrict__ cost,   // [B][G][Q]
                                  unsigned long long* __restrict__ pmin) // [B][G][NTILE]
{
    const int b  = blockIdx.y;
    const int qt = blockIdx.x;
    const int q0 = qt * TQ;
    const int tid = threadIdx.x;

    __shared__ float cent_sh[TQ][GMAX + 1];
    __shared__ float giou_sh[TQ][GMAX + 1];
    __shared__ int lab_sh[GMAX];

    if (tid < GMAX) lab_sh[tid] = labels[b * GMAX + tid];
    const int ng = nact[b];

    {
        const float4* centb = (const float4*)(cent + ((size_t)b * BQ + q0) * GMAX);
        const float4* gioub = (const float4*)(giou + ((size_t)b * BQ + q0) * GMAX);
        int r = tid;   // TQ*GMAX/4 == 256 == BBS
        float4 cv = centb[r];
        float4 gv = gioub[r];
        int e = r * 4;
        int qq = e >> 5;
        int ii = e & (GMAX - 1);
        cent_sh[qq][ii]     = cv.x;
        cent_sh[qq][ii + 1] = cv.y;
        cent_sh[qq][ii + 2] = cv.z;
        cent_sh[qq][ii + 3] = cv.w;
        giou_sh[qq][ii]     = gv.x;
        giou_sh[qq][ii + 1] = gv.y;
        giou_sh[qq][ii + 2] = gv.z;
        giou_sh[qq][ii + 3] = gv.w;
    }
    __syncthreads();

    const int qi = tid & (TQ - 1);
    const int ig = tid >> 5;
    const int q  = q0 + qi;
    const float ho = __fmul_rn(0.5f, objp[b * BQ + q]);
    const float* semrow = sem + ((size_t)b * BQ + q) * NC;

    // issue all sem gathers first (uniform trip count => no divergence) for MLP
    float pc[4];
#pragma unroll
    for (int k = 0; k < 4; k++) {
        int i = ig + 8 * k;
        if (i < ng) pc[k] = semrow[lab_sh[i]];
    }

#pragma unroll
    for (int k = 0; k < 4; k++) {
        int i = ig + 8 * k;
        if (i >= ng) break;
        float ce = cent_sh[qi][i];
        float gi = giou_sh[qi][i];
        float c = __fsub_rn(__fadd_rn(__fsub_rn(-pc[k], ho), ce),
                            __fmul_rn(2.0f, gi));
        __builtin_nontemporal_store(c, &cost[((size_t)b * GMAX + i) * BQ + q]);

        // fused partial (min, first-argmin) over this tile's 32 q's.
        // monotone u32 transform preserves <; u64 min == lex (value, q) min.
        unsigned cbits = __float_as_uint(c);
        unsigned mono  = (cbits & 0x80000000u) ? ~cbits : (cbits | 0x80000000u);
        unsigned long long key = ((unsigned long long)mono << 32) | (unsigned)q;
#pragma unroll
        for (int off = 16; off >= 1; off >>= 1) {
            unsigned long long ok = __shfl_down(key, off, 32);
            if (ok < key) key = ok;
        }
        if (qi == 0) pmin[((size_t)b * GMAX + i) * NTILE + qt] = key;
    }
}

// ---------------- Kernel 2: JV Hungarian solver with greedy warm start ----
// One block per batch. Dual-feasible warm start: u[i] = min_j cost[i][j],
// v = 0; greedy-assign each row to its (first-index) argmin column if free.
// Rows that collide run the exact f64 Dijkstra augmentation (first-index
// tie-break). Complementary slackness holds throughout => final matching is
// the optimal assignment; with continuous random costs the optimum is unique,
// so the output equals the reference's.
__launch_bounds__(BS, 1)
__global__ void matcher_kernel(const float* __restrict__ cost,   // [B][G][Q]
                               const unsigned long long* __restrict__ pmin,
                               const int*   __restrict__ nact,   // [B]
                               float* __restrict__ out)          // [2*B*Q]
{
    const int b    = blockIdx.x;
    const int tid  = threadIdx.x;
    const int m    = BQ;
    const int wave = tid >> 6;
    const int lane = tid & 63;

    __shared__ __align__(16) short p_lds[BQ + 8];       // matched row per col
    __shared__ __align__(16) unsigned short way_lds[BQ];
    __shared__ double u_lds[GMAX];
    __shared__ double   redv[2][NWAVE];
    __shared__ unsigned redpk[2][NWAVE];
    __shared__ int    step_i0[GMAX + 2];
    __shared__ double step_D[GMAX + 2];
    __shared__ float  rmin_v[GMAX];
    __shared__ int    rmin_j[GMAX];
    __shared__ int    unmatched[GMAX];
    __shared__ int    s_nunm;

    {   // vectorized init: 512 threads x 16B == 8192 B == BQ shorts; 16B tail
        int4 mone; mone.x = mone.y = mone.z = mone.w = -1;
        ((int4*)p_lds)[tid] = mone;
        if (tid < 4) ((int*)(p_lds + BQ))[tid] = -1;
    }
    const int ng = nact[b];
    const float* cb = cost + (size_t)b * GMAX * BQ;
    __syncthreads();

    // ---- Pass 1: reduce the build kernel's per-tile partial mins ----------
    // 128 u64 per row: 2 coalesced loads/lane + 6 shuffle steps per row.
    {
        const unsigned long long* pb = pmin + (size_t)b * GMAX * NTILE;
        for (int r = wave; r < ng; r += NWAVE) {
            const unsigned long long* row = pb + (size_t)r * NTILE;
            unsigned long long k0 = row[lane];
            unsigned long long k1 = row[lane + 64];
            unsigned long long key = (k1 < k0) ? k1 : k0;
#pragma unroll
            for (int off = 32; off >= 1; off >>= 1) {
                unsigned long long ok = __shfl_down(key, off, 64);
                if (ok < key) key = ok;
            }
            if (lane == 0) {
                unsigned mono = (unsigned)(key >> 32);
                unsigned bits = (mono & 0x80000000u) ? (mono ^ 0x80000000u) : ~mono;
                rmin_v[r] = __uint_as_float(bits);
                rmin_j[r] = (int)(key & 0xFFFFFFFFu);
            }
        }
    }
    __syncthreads();

    // ---- duals + greedy assignment (thread 0, <=32 iters) ----
    if (tid < ng) u_lds[tid] = (double)rmin_v[tid];
    if (tid == 0) {
        int nu = 0;
        for (int i = 0; i < ng; i++) {
            int j = rmin_j[i];
            if (p_lds[j] < 0) p_lds[j] = (short)i;
            else unmatched[nu++] = i;           // ascending row order
        }
        s_nunm = nu;
    }
    __syncthreads();
    const int nunm = s_nunm;

    const double INF = (double)INFINITY;
    const int jbase = tid * CPT;
    const float4* cb4 = (const float4*)cb;

    double v_reg[CPT], minv[CPT], enterD[CPT];
    int way_reg[CPT], p_reg[CPT];
#pragma unroll
    for (int k = 0; k < CPT; k++) { v_reg[k] = 0.0; way_reg[k] = m; enterD[k] = 0.0; }

    for (int t = 0; t < nunm; t++) {
        const int ri = unmatched[t];

        // refresh p_reg (one ds_read_b128; p constant during the phase)
        int4 pv = ((const int4*)p_lds)[tid];
        p_reg[0] = (int)(short)(pv.x & 0xFFFF); p_reg[1] = pv.x >> 16;
        p_reg[2] = (int)(short)(pv.y & 0xFFFF); p_reg[3] = pv.y >> 16;
        p_reg[4] = (int)(short)(pv.z & 0xFFFF); p_reg[5] = pv.z >> 16;
        p_reg[6] = (int)(short)(pv.w & 0xFFFF); p_reg[7] = pv.w >> 16;

        // initial row load (row ri) + its u
        const float4* r4 = cb4 + (size_t)ri * (BQ / 4) + tid * 2;
        float4 c0 = r4[0];
        float4 c1 = r4[1];
        double ui0 = u_lds[ri];

#pragma unroll
        for (int k = 0; k < CPT; k++) minv[k] = INF;
        unsigned used_mask = 0;
        int i0 = ri, j0 = m, ns = 0, buf = 0, jfin;
        double D = 0.0;

        while (true) {
            float cf[CPT] = {c0.x, c0.y, c0.z, c0.w, c1.x, c1.y, c1.z, c1.w};

            // relax + per-thread lexicographic argmin (ascending k == asc. j)
            double bestv = INF;
            unsigned bestpk = ((unsigned)m << 8);
#pragma unroll
            for (int k = 0; k < CPT; k++) {
                bool un = !((used_mask >> k) & 1u);
                double cur = ((double)cf[k] - ui0) - v_reg[k];
                bool better = un && (cur < minv[k]);
                if (better) { minv[k] = cur; way_reg[k] = j0; }
                double mv = un ? minv[k] : INF;
                if (mv < bestv) {
                    bestv = mv;
                    bestpk = (((unsigned)(jbase + k)) << 8) | (unsigned)(p_reg[k] + 1);
                }
            }

            // wave-level lexicographic (val, packed-j) min
#pragma unroll
            for (int off = 32; off >= 1; off >>= 1) {
                double   ov  = __shfl_down(bestv, off, 64);
                unsigned opk = __shfl_down(bestpk, off, 64);
                if (ov < bestv || (ov == bestv && opk < bestpk)) { bestv = ov; bestpk = opk; }
            }
            if (lane == 0) { redv[buf][wave] = bestv; redpk[buf][wave] = bestpk; }
            __syncthreads();                               // the ONLY barrier

            // redundant final reduce on every thread (LDS broadcast reads)
            double delta = redv[buf][0]; unsigned pk = redpk[buf][0];
#pragma unroll
            for (int w = 1; w < NWAVE; w++) {
                double ov = redv[buf][w]; unsigned opk = redpk[buf][w];
                if (ov < delta || (ov == delta && opk < pk)) { delta = ov; pk = opk; }
            }
            const int j1 = (int)(pk >> 8);
            const int pi = (int)(pk & 0xFFu) - 1;

            if (tid == 0) { step_i0[ns] = i0; step_D[ns] = D; }
            D += delta;
            ns++;

            if (pi < 0) { jfin = j1; break; }

            // prefetch next row + its u under the update shadow
            const float4* n4 = cb4 + (size_t)pi * (BQ / 4) + tid * 2;
            c0 = n4[0];
            c1 = n4[1];
            ui0 = u_lds[pi];

#pragma unroll
            for (int k = 0; k < CPT; k++)
                if (!((used_mask >> k) & 1u)) minv[k] -= delta;

            unsigned kk = (unsigned)(j1 - jbase);
            if (kk < CPT) { used_mask |= (1u << kk); enterD[kk] = D; }

            i0 = pi; j0 = j1; buf ^= 1;
        }

        // closed-form dual updates (same f64 values as per-step updates)
#pragma unroll
        for (int k = 0; k < CPT; k++)
            if ((used_mask >> k) & 1u) { v_reg[k] -= (D - enterD[k]); }

        // dump way_reg as one packed 16B LDS write
        int4 wv;
        wv.x = (way_reg[0] & 0xFFFF) | (way_reg[1] << 16);
        wv.y = (way_reg[2] & 0xFFFF) | (way_reg[3] << 16);
        wv.z = (way_reg[4] & 0xFFFF) | (way_reg[5] << 16);
        wv.w = (way_reg[6] & 0xFFFF) | (way_reg[7] << 16);
        ((int4*)way_lds)[tid] = wv;

        __syncthreads();   // way/step logs visible to all
        if (tid < ns) u_lds[step_i0[tid]] += D - step_D[tid];  // distinct rows
        if (tid == 0) {
            int jc = jfin;
            while (jc != m) {
                int jp = (int)way_lds[jc];
                p_lds[jc] = (jp == m) ? (short)ri : p_lds[jp];
                jc = jp;
            }
        }
        __syncthreads();
    }

    // ---- write outputs: [per_prop (B*Q), mask (B*Q)] as float ----
#pragma unroll
    for (int k = 0; k < CPT; k++) {
        int j = jbase + k;
        short pj = p_lds[j];
        out[(size_t)b * BQ + j] = (pj >= 0) ? (float)pj : 0.0f;
        out[(size_t)NB * BQ + (size_t)b * BQ + j] = (pj >= 0) ? 1.0f : 0.0f;
    }
}

extern "C" void kernel_launch(void* const* d_in, const int* in_sizes, int n_in,
                              void* d_out, int out_size, void* d_ws, size_t ws_size,
                              hipStream_t stream) {
    const float* sem    = (const float*)d_in[0];  // [B,Q,C]
    const float* objp   = (const float*)d_in[1];  // [B,Q]
    const float* cent   = (const float*)d_in[2];  // [B,Q,G]
    const float* giou   = (const float*)d_in[3];  // [B,Q,G]
    const int*   labels = (const int*)d_in[4];    // [B,G]
    const int*   nact   = (const int*)d_in[5];    // [B]
    float* out  = (float*)d_out;                  // [2*B*Q]
    float* cost = (float*)d_ws;                   // [B][G][Q] = 16 MB
    unsigned long long* pmin =
        (unsigned long long*)((char*)d_ws + COST_BYTES);  // [B][G][NTILE] = 1 MB

    dim3 bgrid(NTILE, NB);
    build_cost_kernel<<<bgrid, BBS, 0, stream>>>(sem, objp, cent, giou,
                                                 labels, nact, cost, pmin);
    matcher_kernel<<<NB, BS, 0, stream>>>(cost, pmin, nact, out);
}